// Round 4
// baseline (1189.058 us; speedup 1.0000x reference)
//
#include <hip/hip_runtime.h>

// TreecrfLossSRL: inside algorithm (logsumexp semiring), B=64, N=256.
// Two CYK charts per batch (ob / allv) -> scalar (logz - marg).sum()/denom.
//
// Single start-major triangular chart in LDS (rows padded to x4 floats,
// 133 KB dynamic-LDS opt-in), values scaled by log2(e).
//   left  stream A[i][u],     u=1..w-1 : contiguous, aligned ds_read_b128
//   right stream A[i+u][w-u]           : diagonal walk, incremental 32-bit
//                                        addressing, scattered ds_read_b32
// No global chart copy at all -> no L2 thrash, no write drain at barriers.
// Base-2 domain: exp -> raw v_exp_f32, log -> __log2f.

#define NN 256
#define BATCH 64
#define NCHART (2 * BATCH)
#define NEGV -1000000000.0f
#define NEGB -1.0e30f
#define K2f 1.4426950408889634f   /* log2(e) */
#define LN2f 0.6931471805599453f
#define PADTRI 33280                         /* triangular, rows padded to x4 */
#define LDSF (PADTRI + 16)                   /* +pad absorbs <=3-term overrun */
#define FB_OFF ((size_t)16)
#define RES_OFF (FB_OFF + (size_t)NCHART * LDSF)
#define LEN_OFF (RES_OFF + NCHART)

// padded start-major row offset: sum_{r<i} pad4(N-r)
__device__ __forceinline__ int rop(int i) {
    int r = i & 3;
    int extra = (r == 2) ? 1 : ((r == 3) ? 3 : 0);
    return (i << 8) - ((i * (i - 1)) >> 1) + 6 * (i >> 2) + extra;
}

__device__ __forceinline__ float fexp2(float x) {
#if __has_builtin(__builtin_amdgcn_exp2f)
    return __builtin_amdgcn_exp2f(x);
#else
    return exp2f(x);
#endif
}

// natural-log score at span [i, j] for type t (0 = ob/constrained, 1 = allv)
__device__ __forceinline__ float score_at(const float* __restrict__ logits,
                                          const int* __restrict__ spans_ind,
                                          const void* __restrict__ span_mask,
                                          int isb, int t, int b, int i, int j) {
    size_t sidx = ((size_t)b * NN + i) * NN + j;
    float l0 = logits[2 * sidx];
    float l1 = logits[2 * sidx + 1];
    if (t) {
        float mx = fmaxf(l0, l1), mn = fminf(l0, l1);
        return mx + log1pf(__expf(mn - mx));
    } else {
        bool sind = (spans_ind[sidx] == 2);
        bool sm = isb ? (((const unsigned char*)span_mask)[sidx] != 0)
                      : (((const int*)span_mask)[sidx] != 0);
        float s0 = (sm || sind)  ? NEGV : l0;
        float s1 = (sm || !sind) ? NEGV : l1;
        float mx = fmaxf(s0, s1), mn = fminf(s0, s1);
        return mx + log1pf(__expf(mn - mx));
    }
}

template <bool USE_LDS>
__global__ __launch_bounds__(1024) void cyk_kernel(
    const float* __restrict__ logits,     // [B,N,N,2] f32
    const int* __restrict__ spans_ind,    // [B,N,N] i32
    const void* __restrict__ maskspan,    // [B,N,N] bool (byte or i32)
    const void* __restrict__ span_mask,   // [B,N,N] bool
    float* __restrict__ ws) {
    extern __shared__ float lds[];
    const int c = blockIdx.x;
    const int b = c >> 1;
    const int t = c & 1;
    const int tid = threadIdx.x;
    float* __restrict__ L = USE_LDS ? lds : (ws + FB_OFF + (size_t)c * LDSF);

    __shared__ int s_len;
    __shared__ int s_isb;
    if (tid == 0) {
        s_len = 0;
        unsigned probe = *(const unsigned*)maskspan;
        s_isb = (probe > 1u) ? 1 : 0;  // byte-packed bools -> 0x01010101
    }
    __syncthreads();
    const int isb = s_isb;

    // lens[b] = sum_j maskspan[b,0,j]
    if (tid < NN) {
        size_t off = (size_t)b * NN * NN + tid;
        int v = isb ? (((const unsigned char*)maskspan)[off] ? 1 : 0)
                    : (((const int*)maskspan)[off] ? 1 : 0);
        atomicAdd(&s_len, v);
    }

    // width-1 init (base-2 domain): row i, col 0
    if (tid < NN) {
        L[rop(tid)] = K2f *
            score_at(logits, spans_ind, span_mask, isb, t, b, tid, tid);
    }
    __syncthreads();

    for (int w = 2; w <= NN; ++w) {
        const int T = w - 1;          // split points
        const int E = NN - w + 1;     // valid entries
        int P = 1024 / E;             // pow2 sub-lanes per entry, P*E <= 1024
        int sh;
        if (P >= 64) { P = 64; sh = 6; }
        else { sh = 31 - __clz(P); P = 1 << sh; }
        const int g = tid >> sh;
        const int s = tid & (P - 1);

        if (g < E) {
            const float* __restrict__ Lrow = L + rop(g);
            const int j = g + T;
            // prefetch D score early (only the writer lane needs it)
            float dsc = 0.0f;
            if (s == 0)
                dsc = K2f * score_at(logits, spans_ind, span_mask, isb, t, b, g, j);

            const int per = (((T + P - 1) >> sh) + 3) & ~3;   // x4 chunk
            const int q0 = s * per;
            const int q1 = min(q0 + per, T);
            float m = NEGB, sum = 0.0f;
            // right-stream diagonal walk: term q (u=q+1) lives at
            // rop(g+q+1) + (w - q - 2); incremental across terms.
            int row = g + 1 + q0;
            int ra = rop(row) + (w - 2 - q0);
            for (int q = q0; q < q1; q += 4) {
                float4 lv = *(const float4*)(Lrow + q);   // aligned b128
                int a0 = ra;
                int a1 = a0 + (((259 - row) & ~3) - 1);
                int a2 = a1 + (((258 - row) & ~3) - 1);
                int a3 = a2 + (((257 - row) & ~3) - 1);
                float r0 = L[a0], r1 = L[a1], r2 = L[a2], r3 = L[a3];
                ra = a3 + (((256 - row) & ~3) - 1);
                row += 4;
                float t0 = lv.x + r0;
                float t1 = (q + 1 < q1) ? (lv.y + r1) : NEGB;
                float t2 = (q + 2 < q1) ? (lv.z + r2) : NEGB;
                float t3 = (q + 3 < q1) ? (lv.w + r3) : NEGB;
                float gm = fmaxf(fmaxf(t0, t1), fmaxf(t2, t3));
                float nm = fmaxf(m, gm);
                sum = sum * fexp2(m - nm)
                    + fexp2(t0 - nm) + fexp2(t1 - nm)
                    + fexp2(t2 - nm) + fexp2(t3 - nm);
                m = nm;
            }
            // wave-local (m,sum) butterfly across P contiguous sub-lanes
            for (int d = P >> 1; d > 0; d >>= 1) {
                float m2 = __shfl_xor(m, d);
                float s2 = __shfl_xor(sum, d);
                float mn = fmaxf(m, m2);
                sum = sum * fexp2(m - mn) + s2 * fexp2(m2 - mn);
                m = mn;
            }
            if (s == 0) {
                L[rop(g) + T] = dsc + m + __log2f(sum);  // row g, col w-1
            }
        }
        __syncthreads();
    }

    if (tid == 0) {
        int len = s_len;
        float r = (len >= 1) ? (L[len - 1] * LN2f) : NEGV;  // row 0, col len-1
        ws[RES_OFF + c] = r;
        if (t == 0) ws[LEN_OFF + b] = (float)len;
    }
}

__global__ __launch_bounds__(64) void finish_kernel(const float* __restrict__ ws,
                                                    float* __restrict__ out) {
    int b = threadIdx.x;  // 0..63
    float diff = ws[RES_OFF + 2 * b + 1] - ws[RES_OFF + 2 * b];
    float len  = ws[LEN_OFF + b];
    for (int d = 32; d > 0; d >>= 1) {
        diff += __shfl_xor(diff, d);
        len  += __shfl_xor(len, d);
    }
    if (b == 0) out[0] = diff / len;
}

extern "C" void kernel_launch(void* const* d_in, const int* in_sizes, int n_in,
                              void* d_out, int out_size, void* d_ws, size_t ws_size,
                              hipStream_t stream) {
    const float* logits    = (const float*)d_in[0];
    const int*   spans_ind = (const int*)d_in[1];
    const void*  maskspan  = d_in[2];
    const void*  span_mask = d_in[3];
    float* ws = (float*)d_ws;

    const size_t shbytes = (size_t)LDSF * sizeof(float);  // 133184 B
    hipError_t e = hipFuncSetAttribute(
        reinterpret_cast<const void*>(&cyk_kernel<true>),
        hipFuncAttributeMaxDynamicSharedMemorySize, (int)shbytes);
    if (e == hipSuccess) {
        hipLaunchKernelGGL(cyk_kernel<true>, dim3(NCHART), dim3(1024), shbytes,
                           stream, logits, spans_ind, maskspan, span_mask, ws);
    } else {
        hipLaunchKernelGGL(cyk_kernel<false>, dim3(NCHART), dim3(1024), 0,
                           stream, logits, spans_ind, maskspan, span_mask, ws);
    }
    hipLaunchKernelGGL(finish_kernel, dim3(1), dim3(64), 0, stream,
                       ws, (float*)d_out);
}

// Round 5
// 948.755 us; speedup vs baseline: 1.2533x; 1.2533x over previous
//
#include <hip/hip_runtime.h>

// TreecrfLossSRL: inside algorithm (logsumexp semiring), B=64, N=256.
// Two CYK charts per batch (ob / allv) -> scalar (logz - marg).sum()/denom.
//
// Width-major (column-major) triangular chart in LDS, columns padded to x4
// floats, values scaled by log2(e). At level w, a wave processes ONE split u
// across 64..128 consecutive entries g:
//    left  = col[u]   + g        (consecutive across lanes)
//    right = col[w-u] + g + u    (consecutive across lanes)
// -> conflict-free ds_read2_b32 (each lane covers 2 adjacent entries).
// u-range is chunked across waves (and sub-lane groups for small E);
// per-entry (m,sum) partials combine via LDS scratch + 1 extra barrier.
// D-scores prefetched as raw registers at level top (latency hidden).

#define NN 256
#define BATCH 64
#define NCHART (2 * BATCH)
#define NEGV -1000000000.0f
#define NEGB -1.0e30f
#define K2f 1.4426950408889634f   /* log2(e) */
#define LN2f 0.6931471805599453f

#define CHARTF 33280                   /* sum of pad4(257-v), v=1..256 */
#define CST_OFF 33280                  /* int table, 257 used, pad to 264 */
#define SCR_OFF (CHARTF + 264)         /* float2 scratch, 2048 pairs */
#define LDSF (SCR_OFF + 4096)          /* 37640 floats = 150560 B */

#define RES_OFF ((size_t)16)
#define LEN_OFF ((size_t)(16 + NCHART))
#define FB_OFF  ((size_t)(16 + NCHART + BATCH + 16))

__device__ __forceinline__ float fexp2(float x) {
#if __has_builtin(__builtin_amdgcn_exp2f)
    return __builtin_amdgcn_exp2f(x);
#else
    return exp2f(x);
#endif
}

// column start (floats) for column v (width v), v in 1..256
__device__ __forceinline__ int cstart_calc(int v) {
    int n = v - 1;
    if (n <= 0) return 0;
    int a = 258 - v;
    int s1 = ((a + 256) * n) >> 1;          // sum y, y=a..256
    int full = n >> 2, s2 = full * 6;       // pad4 remainders
    int y = a + (full << 2);
    for (int k = 0; k < (n & 3); k++) s2 += (-(y + k)) & 3;
    return s1 + s2;
}

// natural-log score at span [i, j] for type t (0 = ob/constrained, 1 = allv)
__device__ __forceinline__ float score_at(const float* __restrict__ logits,
                                          const int* __restrict__ spans_ind,
                                          const void* __restrict__ span_mask,
                                          int isb, int t, int b, int i, int j) {
    size_t sidx = ((size_t)b * NN + i) * NN + j;
    float l0 = logits[2 * sidx];
    float l1 = logits[2 * sidx + 1];
    if (t) {
        float mx = fmaxf(l0, l1), mn = fminf(l0, l1);
        return mx + log1pf(__expf(mn - mx));
    } else {
        bool sind = (spans_ind[sidx] == 2);
        bool sm = isb ? (((const unsigned char*)span_mask)[sidx] != 0)
                      : (((const int*)span_mask)[sidx] != 0);
        float s0 = (sm || sind)  ? NEGV : l0;
        float s1 = (sm || !sind) ? NEGV : l1;
        float mx = fmaxf(s0, s1), mn = fminf(s0, s1);
        return mx + log1pf(__expf(mn - mx));
    }
}

#define ONLINE(MM, SS, TT)                                     \
    {                                                          \
        float nm_ = fmaxf(MM, TT);                             \
        SS = SS * fexp2(MM - nm_) + fexp2(TT - nm_);           \
        MM = nm_;                                              \
    }

template <bool USE_LDS>
__global__ __launch_bounds__(1024) void cyk_kernel(
    const float* __restrict__ logits,     // [B,N,N,2] f32
    const int* __restrict__ spans_ind,    // [B,N,N] i32
    const void* __restrict__ maskspan,    // [B,N,N] bool (byte or i32)
    const void* __restrict__ span_mask,   // [B,N,N] bool
    float* __restrict__ ws) {
    extern __shared__ float lds[];
    const int c = blockIdx.x;
    const int b = c >> 1;
    const int t = c & 1;
    const int tid = threadIdx.x;
    const int wave = tid >> 6, lane = tid & 63;

    float* __restrict__ Lc = USE_LDS ? lds : (ws + FB_OFF + (size_t)c * LDSF);
    int* __restrict__ cstp = (int*)(Lc + CST_OFF);
    float2* __restrict__ scr = (float2*)(Lc + SCR_OFF);

    __shared__ int s_len;
    __shared__ int s_isb;
    if (tid == 0) {
        s_len = 0;
        unsigned probe = *(const unsigned*)maskspan;
        s_isb = (probe > 1u) ? 1 : 0;  // byte-packed bools -> 0x01010101
    }
    __syncthreads();
    const int isb = s_isb;

    // column-start table
    if (tid <= NN) cstp[tid] = cstart_calc(tid);

    // lens[b] = sum_j maskspan[b,0,j]
    if (tid < NN) {
        size_t off = (size_t)b * NN * NN + tid;
        int v = isb ? (((const unsigned char*)maskspan)[off] ? 1 : 0)
                    : (((const int*)maskspan)[off] ? 1 : 0);
        atomicAdd(&s_len, v);
    }

    // width-1 column init (base-2 domain): col 1 starts at 0
    if (tid < NN) {
        Lc[tid] = K2f *
            score_at(logits, spans_ind, span_mask, isb, t, b, tid, tid);
    }
    __syncthreads();

    for (int w = 2; w <= NN; ++w) {
        const int T = w - 1;          // split points u = 1..T
        const int E = NN + 1 - w;     // entries

        // ---- prefetch raw D-score inputs for entry tid (used in finalize)
        float dl0 = 0.f, dl1 = 0.f; int dsi = 0, dsm = 0;
        if (tid < E) {
            size_t sidx = ((size_t)b * NN + tid) * NN + (tid + T);
            dl0 = logits[2 * sidx];
            dl1 = logits[2 * sidx + 1];
            if (t == 0) {
                dsi = spans_ind[sidx];
                dsm = isb ? (int)(((const unsigned char*)span_mask)[sidx])
                          : (((const int*)span_mask)[sidx]);
            }
        }

        // ---- wave config
        int tile, wv, W, Wsh;
        if (E > 128) { tile = wave >> 3; wv = wave & 7; W = 8;  Wsh = 3; }
        else         { tile = 0;         wv = wave;     W = 16; Wsh = 4; }
        const int tbase = tile << 7;
        const int ET = min(E - tbase, 128);        // entries in this tile
        const int hE = (ET + 1) >> 1;              // lane-pairs needed
        const int EH = (hE <= 1) ? 1 : (1 << (32 - __clz(hE - 1)));
        const int sh2 = (EH == 1) ? 0 : (31 - __clz(EH));
        const int sh_p = 6 - sh2;
        const int P = 1 << sh_p;                   // u's in flight per wave
        const int r = lane & (EH - 1), p = lane >> sh2;
        const int g = tbase + (r << 1);
        const bool gv0 = (g < E), gv1 = (g + 1 < E);

        const int C = (T + W - 1) >> Wsh;          // u-chunk per wave
        const int u0 = 1 + wv * C;
        const int u1 = min(u0 + C, w);             // exclusive
        const int CL = u1 - u0;

        float m0 = NEGB, s0acc = 0.f, m1 = NEGB, s1acc = 0.f;

        if (CL > 0) {
            const int steps = (CL + P - 1) >> sh_p;
            int u = u0 + p;
            int uc = min(u, T);
            int la = cstp[uc] + g;
            int vv = w - uc;
            int ra = cstp[vv] + g + uc;

            if (P >= 4) {
                const int B1 = ((3 * P) >> 1) - ((P * (P - 1)) >> 1);
                const int PP = P << sh_p;
                int dl = ((257 - uc) << sh_p) + B1;
                int dr = -(((257 - vv + P) << sh_p) + B1) + P;
                for (int it = 0; it < steps; ++it) {
                    float l0 = Lc[la], l1 = Lc[la + 1];
                    float rr0 = Lc[ra], rr1 = Lc[ra + 1];
                    bool uv = (u < u1);
                    float t0 = (uv && gv0) ? (l0 + rr0) : NEGB;
                    float t1 = (uv && gv1) ? (l1 + rr1) : NEGB;
                    ONLINE(m0, s0acc, t0);
                    ONLINE(m1, s1acc, t1);
                    la += dl; dl -= PP;
                    ra += dr; dr -= PP;
                    ra = max(ra, 0);
                    u += P;
                }
            } else if (P == 2) {
                for (int it = 0; it < steps; ++it) {
                    float l0 = Lc[la], l1 = Lc[la + 1];
                    float rr0 = Lc[ra], rr1 = Lc[ra + 1];
                    bool uv = (u < u1);
                    float t0 = (uv && gv0) ? (l0 + rr0) : NEGB;
                    float t1 = (uv && gv1) ? (l1 + rr1) : NEGB;
                    ONLINE(m0, s0acc, t0);
                    ONLINE(m1, s1acc, t1);
                    la += ((260 - u) & ~3) + ((259 - u) & ~3);
                    ra -= (((261 - vv) & ~3) + ((262 - vv) & ~3)) - 2;
                    ra = max(ra, 0);
                    u += 2; vv -= 2;
                }
            } else {  // P == 1: the bulk of the work (E >= 65)
                for (int it = 0; it < steps; ++it) {
                    float l0 = Lc[la], l1 = Lc[la + 1];
                    float rr0 = Lc[ra], rr1 = Lc[ra + 1];
                    float t0 = gv0 ? (l0 + rr0) : NEGB;
                    float t1 = gv1 ? (l1 + rr1) : NEGB;
                    ONLINE(m0, s0acc, t0);
                    ONLINE(m1, s1acc, t1);
                    la += (260 - u) & ~3;
                    ra -= ((261 - vv) & ~3) - 1;
                    ra = max(ra, 0);
                    u += 1; vv -= 1;
                }
            }

            // butterfly across the P sub-lane groups (same r, different p)
            for (int d = 32; d >= EH; d >>= 1) {
                float mm = __shfl_xor(m0, d);
                float ss = __shfl_xor(s0acc, d);
                float nm = fmaxf(m0, mm);
                s0acc = s0acc * fexp2(m0 - nm) + ss * fexp2(mm - nm);
                m0 = nm;
                mm = __shfl_xor(m1, d);
                ss = __shfl_xor(s1acc, d);
                nm = fmaxf(m1, mm);
                s1acc = s1acc * fexp2(m1 - nm) + ss * fexp2(mm - nm);
                m1 = nm;
            }
        }

        // one partial per (entry, wave)
        if (p == 0) {
            if (gv0) scr[g * W + wv] = make_float2(m0, s0acc);
            if (gv1) scr[(g + 1) * W + wv] = make_float2(m1, s1acc);
        }
        __syncthreads();

        // ---- finalize: entry e = tid combines W partials + D, writes col w
        if (tid < E) {
            const float2* pp = scr + (size_t)tid * W;
            float m = NEGB, s = 0.f;
            for (int k = 0; k < W; ++k) {
                float2 q = pp[k];
                float nm = fmaxf(m, q.x);
                s = s * fexp2(m - nm) + q.y * fexp2(q.x - nm);
                m = nm;
            }
            float sc;
            if (t) {
                float mx = fmaxf(dl0, dl1), mn = fminf(dl0, dl1);
                sc = mx + log1pf(__expf(mn - mx));
            } else {
                bool si = (dsi == 2);
                bool smv = (dsm != 0);
                float a0 = (smv || si)  ? NEGV : dl0;
                float a1 = (smv || !si) ? NEGV : dl1;
                float mx = fmaxf(a0, a1), mn = fminf(a0, a1);
                sc = mx + log1pf(__expf(mn - mx));
            }
            Lc[cstp[w] + tid] = K2f * sc + m + __log2f(s);
        }
        __syncthreads();
    }

    if (tid == 0) {
        int len = s_len;
        float rres = (len >= 1) ? (Lc[cstp[len]] * LN2f) : NEGV;
        ws[RES_OFF + c] = rres;
        if (t == 0) ws[LEN_OFF + b] = (float)len;
    }
}

__global__ __launch_bounds__(64) void finish_kernel(const float* __restrict__ ws,
                                                    float* __restrict__ out) {
    int b = threadIdx.x;  // 0..63
    float diff = ws[RES_OFF + 2 * b + 1] - ws[RES_OFF + 2 * b];
    float len  = ws[LEN_OFF + b];
    for (int d = 32; d > 0; d >>= 1) {
        diff += __shfl_xor(diff, d);
        len  += __shfl_xor(len, d);
    }
    if (b == 0) out[0] = diff / len;
}

extern "C" void kernel_launch(void* const* d_in, const int* in_sizes, int n_in,
                              void* d_out, int out_size, void* d_ws, size_t ws_size,
                              hipStream_t stream) {
    const float* logits    = (const float*)d_in[0];
    const int*   spans_ind = (const int*)d_in[1];
    const void*  maskspan  = d_in[2];
    const void*  span_mask = d_in[3];
    float* ws = (float*)d_ws;

    const size_t shbytes = (size_t)LDSF * sizeof(float);  // 150560 B
    hipError_t e = hipFuncSetAttribute(
        reinterpret_cast<const void*>(&cyk_kernel<true>),
        hipFuncAttributeMaxDynamicSharedMemorySize, (int)shbytes);
    if (e == hipSuccess) {
        hipLaunchKernelGGL(cyk_kernel<true>, dim3(NCHART), dim3(1024), shbytes,
                           stream, logits, spans_ind, maskspan, span_mask, ws);
    } else {
        hipLaunchKernelGGL(cyk_kernel<false>, dim3(NCHART), dim3(1024), 0,
                           stream, logits, spans_ind, maskspan, span_mask, ws);
    }
    hipLaunchKernelGGL(finish_kernel, dim3(1), dim3(64), 0, stream,
                       ws, (float*)d_out);
}

// Round 6
// 746.151 us; speedup vs baseline: 1.5936x; 1.2715x over previous
//
#include <hip/hip_runtime.h>

// TreecrfLossSRL: inside algorithm (logsumexp semiring), B=64, N=256.
// Two CYK charts per batch (ob / allv) -> scalar (logz - marg).sum()/denom.
//
// Width-major triangular chart in LDS, NO padding (col v starts at
// cst(v) = 257(v-1) - v(v-1)/2, closed form). Values scaled by log2(e).
// At level w, lane l accumulates entries g = l + 64k (k < K = ceil(E/64)):
//   left  = Lc[cst(u)   + g]      -> stride-1 across lanes (conflict-free)
//   right = Lc[cst(w-u) + u + g]  -> stride-1 across lanes (conflict-free)
// +64k offsets are ds_read2st64-fusable. u-range split across 16 waves
// (sub-grouped when E < 64); per-(entry,wave) partial stored compressed as
// m + log2(s) in transposed scratch scr[wave*256 + g] (stride-1 both ways).

#define NN 256
#define BATCH 64
#define NCHART (2 * BATCH)
#define NEGV -1000000000.0f
#define NEGB -1.0e30f
#define K2f 1.4426950408889634f   /* log2(e) */
#define LN2f 0.6931471805599453f

#define CHARTF 32896                   /* triangular chart, no padding */
#define SCR_OFF CHARTF                 /* 16 waves x 256 entries, f32 */
#define LDSF (CHARTF + 4096)           /* 36992 floats = 147968 B */

#define RES_OFF ((size_t)16)
#define LEN_OFF ((size_t)(16 + NCHART))
#define FB_OFF  ((size_t)(16 + NCHART + BATCH + 16))

__device__ __forceinline__ float fexp2(float x) {
#if __has_builtin(__builtin_amdgcn_exp2f)
    return __builtin_amdgcn_exp2f(x);
#else
    return exp2f(x);
#endif
}

// column start (floats) for width v, v in 1..256
__device__ __forceinline__ int cstart(int v) {
    return 257 * (v - 1) - ((v * (v - 1)) >> 1);
}

// natural-log score at span [i, j] for type t (0 = ob/constrained, 1 = allv)
__device__ __forceinline__ float score_at(const float* __restrict__ logits,
                                          const int* __restrict__ spans_ind,
                                          const void* __restrict__ span_mask,
                                          int isb, int t, int b, int i, int j) {
    size_t sidx = ((size_t)b * NN + i) * NN + j;
    float l0 = logits[2 * sidx];
    float l1 = logits[2 * sidx + 1];
    if (t) {
        float mx = fmaxf(l0, l1), mn = fminf(l0, l1);
        return mx + log1pf(__expf(mn - mx));
    } else {
        bool sind = (spans_ind[sidx] == 2);
        bool sm = isb ? (((const unsigned char*)span_mask)[sidx] != 0)
                      : (((const int*)span_mask)[sidx] != 0);
        float s0 = (sm || sind)  ? NEGV : l0;
        float s1 = (sm || !sind) ? NEGV : l1;
        float mx = fmaxf(s0, s1), mn = fminf(s0, s1);
        return mx + log1pf(__expf(mn - mx));
    }
}

template <bool USE_LDS>
__global__ __launch_bounds__(1024) void cyk_kernel(
    const float* __restrict__ logits,     // [B,N,N,2] f32
    const int* __restrict__ spans_ind,    // [B,N,N] i32
    const void* __restrict__ maskspan,    // [B,N,N] bool (byte or i32)
    const void* __restrict__ span_mask,   // [B,N,N] bool
    float* __restrict__ ws) {
    extern __shared__ float lds[];
    const int c = blockIdx.x;
    const int b = c >> 1;
    const int t = c & 1;
    const int tid = threadIdx.x;
    const int wave = tid >> 6, lane = tid & 63;

    float* __restrict__ Lc = USE_LDS ? lds : (ws + FB_OFF + (size_t)c * LDSF);
    float* __restrict__ scr = Lc + SCR_OFF;

    __shared__ int s_len;
    __shared__ int s_isb;
    if (tid == 0) {
        s_len = 0;
        unsigned probe = *(const unsigned*)maskspan;
        s_isb = (probe > 1u) ? 1 : 0;  // byte-packed bools -> 0x01010101
    }
    __syncthreads();
    const int isb = s_isb;

    // lens[b] = sum_j maskspan[b,0,j]
    if (tid < NN) {
        size_t off = (size_t)b * NN * NN + tid;
        int v = isb ? (((const unsigned char*)maskspan)[off] ? 1 : 0)
                    : (((const int*)maskspan)[off] ? 1 : 0);
        atomicAdd(&s_len, v);
    }

    // width-1 column init (base-2 domain): col 1 starts at 0
    if (tid < NN) {
        Lc[tid] = K2f *
            score_at(logits, spans_ind, span_mask, isb, t, b, tid, tid);
    }
    __syncthreads();

    for (int w = 2; w <= NN; ++w) {
        const int T = w - 1;          // split points u = 1..T
        const int E = NN + 1 - w;     // entries

        // ---- prefetch raw D-score inputs for entry tid (used in finalize)
        float dl0 = 0.f, dl1 = 0.f; int dsi = 0, dsm = 0;
        if (tid < E) {
            size_t sidx = ((size_t)b * NN + tid) * NN + (tid + T);
            dl0 = logits[2 * sidx];
            dl1 = logits[2 * sidx + 1];
            if (t == 0) {
                dsi = spans_ind[sidx];
                dsm = isb ? (int)(((const unsigned char*)span_mask)[sidx])
                          : (((const int*)span_mask)[sidx]);
            }
        }

        // ---- per-wave / sub-group configuration (all wave-uniform except g)
        int KK, g, slot, slots_sh, EH, sh2;
        if (E > 64) {
            KK = (E + 63) >> 6;       // 2..4 register-blocked entries per lane
            g = lane;
            slot = wave; slots_sh = 4;
            EH = 64; sh2 = 6;
        } else {
            KK = 1;
            EH = (E <= 1) ? 1 : (1 << (32 - __clz(E - 1)));   // pow2 >= E
            sh2 = 31 - __clz(EH);
            g = lane & (EH - 1);
            slot = (wave << (6 - sh2)) + (lane >> sh2);
            slots_sh = 10 - sh2;      // log2(16 * P), P = 64 >> sh2
        }
        const int C = (T + (1 << slots_sh) - 1) >> slots_sh;  // u-chunk
        const int u0 = 1 + slot * C;
        const int u1 = min(u0 + C, w);
        int steps = u1 - u0;

        float M[4] = {NEGB, NEGB, NEGB, NEGB};
        float S[4] = {0.f, 0.f, 0.f, 0.f};

        if (steps > 0) {
            const int v0 = w - u0;
            int la = cstart(u0) + g;
            int ra = cstart(v0) + g + u0;
            int dl = 257 - u0;        // la(u+1) = la + dl
            int dr = 257 - v0;        // ra(u+1) = ra - dr
            for (int it = steps >> 1; it > 0; --it) {
                float l0[4], r0[4], l1[4], r1[4];
#pragma unroll
                for (int k = 0; k < 4; ++k) if (k < KK) {
                    l0[k] = Lc[la + 64 * k];
                    r0[k] = Lc[ra + 64 * k];
                    l1[k] = Lc[la + dl + 64 * k];
                    r1[k] = Lc[ra - dr + 64 * k];
                }
#pragma unroll
                for (int k = 0; k < 4; ++k) if (k < KK) {
                    float t0 = l0[k] + r0[k];
                    float t1 = l1[k] + r1[k];
                    float tm = fmaxf(t0, t1);
                    float nm = fmaxf(M[k], tm);
                    S[k] = S[k] * fexp2(M[k] - nm)
                         + (fexp2(t0 - nm) + fexp2(t1 - nm));
                    M[k] = nm;
                }
                la += 2 * dl - 1; dl -= 2;
                ra -= 2 * dr + 1; dr += 2;
            }
            if (steps & 1) {
#pragma unroll
                for (int k = 0; k < 4; ++k) if (k < KK) {
                    float t0 = Lc[la + 64 * k] + Lc[ra + 64 * k];
                    float nm = fmaxf(M[k], t0);
                    S[k] = S[k] * fexp2(M[k] - nm) + fexp2(t0 - nm);
                    M[k] = nm;
                }
            }
        }

        // butterfly across sub-groups (same g, different u-chunks), K==1 only
        if (EH < 64) {
            for (int d = 32; d >= EH; d >>= 1) {
                float mm = __shfl_xor(M[0], d);
                float ss = __shfl_xor(S[0], d);
                float nm = fmaxf(M[0], mm);
                S[0] = S[0] * fexp2(M[0] - nm) + ss * fexp2(mm - nm);
                M[0] = nm;
            }
        }

        // compressed partial per (wave, entry): m + log2(s)  [stride-1 write]
        if (KK == 1) {
            if ((lane >> sh2) == 0)
                scr[(wave << 8) + g] = M[0] + __log2f(S[0]);
        } else {
#pragma unroll
            for (int k = 0; k < 4; ++k) if (k < KK)
                scr[(wave << 8) + lane + (k << 6)] = M[k] + __log2f(S[k]);
        }
        __syncthreads();

        // ---- finalize: entry tid combines 16 wave-partials + D, writes col w
        if (tid < E) {
            float m = NEGB, ss = 0.f;
#pragma unroll
            for (int wv = 0; wv < 16; ++wv) {
                float pv = scr[(wv << 8) + tid];   // stride-1 across lanes
                float nm = fmaxf(m, pv);
                ss = ss * fexp2(m - nm) + fexp2(pv - nm);
                m = nm;
            }
            float sc;
            if (t) {
                float mx = fmaxf(dl0, dl1), mn = fminf(dl0, dl1);
                sc = mx + log1pf(__expf(mn - mx));
            } else {
                bool si = (dsi == 2);
                bool smv = (dsm != 0);
                float a0 = (smv || si)  ? NEGV : dl0;
                float a1 = (smv || !si) ? NEGV : dl1;
                float mx = fmaxf(a0, a1), mn = fminf(a0, a1);
                sc = mx + log1pf(__expf(mn - mx));
            }
            Lc[cstart(w) + tid] = K2f * sc + m + __log2f(ss);
        }
        __syncthreads();
    }

    if (tid == 0) {
        int len = s_len;
        float rres = (len >= 1) ? (Lc[cstart(len)] * LN2f) : NEGV;
        ws[RES_OFF + c] = rres;
        if (t == 0) ws[LEN_OFF + b] = (float)len;
    }
}

__global__ __launch_bounds__(64) void finish_kernel(const float* __restrict__ ws,
                                                    float* __restrict__ out) {
    int b = threadIdx.x;  // 0..63
    float diff = ws[RES_OFF + 2 * b + 1] - ws[RES_OFF + 2 * b];
    float len  = ws[LEN_OFF + b];
    for (int d = 32; d > 0; d >>= 1) {
        diff += __shfl_xor(diff, d);
        len  += __shfl_xor(len, d);
    }
    if (b == 0) out[0] = diff / len;
}

extern "C" void kernel_launch(void* const* d_in, const int* in_sizes, int n_in,
                              void* d_out, int out_size, void* d_ws, size_t ws_size,
                              hipStream_t stream) {
    const float* logits    = (const float*)d_in[0];
    const int*   spans_ind = (const int*)d_in[1];
    const void*  maskspan  = d_in[2];
    const void*  span_mask = d_in[3];
    float* ws = (float*)d_ws;

    const size_t shbytes = (size_t)LDSF * sizeof(float);  // 147968 B
    hipError_t e = hipFuncSetAttribute(
        reinterpret_cast<const void*>(&cyk_kernel<true>),
        hipFuncAttributeMaxDynamicSharedMemorySize, (int)shbytes);
    if (e == hipSuccess) {
        hipLaunchKernelGGL(cyk_kernel<true>, dim3(NCHART), dim3(1024), shbytes,
                           stream, logits, spans_ind, maskspan, span_mask, ws);
    } else {
        hipLaunchKernelGGL(cyk_kernel<false>, dim3(NCHART), dim3(1024), 0,
                           stream, logits, spans_ind, maskspan, span_mask, ws);
    }
    hipLaunchKernelGGL(finish_kernel, dim3(1), dim3(64), 0, stream,
                       ws, (float*)d_out);
}

// Round 7
// 620.022 us; speedup vs baseline: 1.9178x; 1.2034x over previous
//
#include <hip/hip_runtime.h>

// TreecrfLossSRL: inside algorithm (logsumexp semiring), B=64, N=256.
// Two CYK charts per batch (ob / allv) -> scalar (logz - marg).sum()/denom.
//
// Width-major triangular chart in LDS (col v starts at cst(v), closed form),
// values scaled by log2(e). Lane l accumulates entries g = l + 64k:
// stride-1 across lanes for both streams -> conflict-free (proved r6: 3.8e5).
// Round 7: compile-time KK phases (4/3/2/small), unroll-4 u with two-pass
// softmax (1 rescale per 4 terms), tree finalize (16 trans, short chain).

#define NN 256
#define BATCH 64
#define NCHART (2 * BATCH)
#define NEGV -1000000000.0f
#define NEGB -1.0e30f
#define K2f 1.4426950408889634f   /* log2(e) */
#define LN2f 0.6931471805599453f

#define CHARTF 32896                   /* triangular chart, no padding */
#define SCR_OFF CHARTF                 /* 16 waves x 256 entries, f32 */
#define LDSF (CHARTF + 4096)           /* 36992 floats = 147968 B */

#define RES_OFF ((size_t)16)
#define LEN_OFF ((size_t)(16 + NCHART))
#define FB_OFF  ((size_t)(16 + NCHART + BATCH + 16))

__device__ __forceinline__ float fexp2(float x) {
#if __has_builtin(__builtin_amdgcn_exp2f)
    return __builtin_amdgcn_exp2f(x);
#else
    return exp2f(x);
#endif
}

// column start (floats) for width v, v in 1..256
__device__ __forceinline__ int cstart(int v) {
    return 257 * (v - 1) - ((v * (v - 1)) >> 1);
}

// natural-log score at span [i, j] for type t (0 = ob/constrained, 1 = allv)
__device__ __forceinline__ float score_at(const float* __restrict__ logits,
                                          const int* __restrict__ spans_ind,
                                          const void* __restrict__ span_mask,
                                          int isb, int t, int b, int i, int j) {
    size_t sidx = ((size_t)b * NN + i) * NN + j;
    float l0 = logits[2 * sidx];
    float l1 = logits[2 * sidx + 1];
    if (t) {
        float mx = fmaxf(l0, l1), mn = fminf(l0, l1);
        return mx + log1pf(__expf(mn - mx));
    } else {
        bool sind = (spans_ind[sidx] == 2);
        bool sm = isb ? (((const unsigned char*)span_mask)[sidx] != 0)
                      : (((const int*)span_mask)[sidx] != 0);
        float s0 = (sm || sind)  ? NEGV : l0;
        float s1 = (sm || !sind) ? NEGV : l1;
        float mx = fmaxf(s0, s1), mn = fminf(s0, s1);
        return mx + log1pf(__expf(mn - mx));
    }
}

// combine 16 wave partials (tree) + D score, write chart col w
__device__ __forceinline__ void finalize_level(
    float* __restrict__ Lc, const float* __restrict__ scr,
    int w, int E, int tid, int t,
    float dl0, float dl1, int dsi, int dsm) {
    if (tid < E) {
        float p[16];
#pragma unroll
        for (int i = 0; i < 16; ++i) p[i] = scr[(i << 8) + tid];
        float m = fmaxf(
            fmaxf(fmaxf(fmaxf(p[0], p[1]), fmaxf(p[2], p[3])),
                  fmaxf(fmaxf(p[4], p[5]), fmaxf(p[6], p[7]))),
            fmaxf(fmaxf(fmaxf(p[8], p[9]), fmaxf(p[10], p[11])),
                  fmaxf(fmaxf(p[12], p[13]), fmaxf(p[14], p[15]))));
        float ss =
            ((fexp2(p[0] - m) + fexp2(p[1] - m)) +
             (fexp2(p[2] - m) + fexp2(p[3] - m))) +
            ((fexp2(p[4] - m) + fexp2(p[5] - m)) +
             (fexp2(p[6] - m) + fexp2(p[7] - m))) +
            ((fexp2(p[8] - m) + fexp2(p[9] - m)) +
             (fexp2(p[10] - m) + fexp2(p[11] - m))) +
            ((fexp2(p[12] - m) + fexp2(p[13] - m)) +
             (fexp2(p[14] - m) + fexp2(p[15] - m)));
        float sc;
        if (t) {
            float mx = fmaxf(dl0, dl1), mn = fminf(dl0, dl1);
            sc = mx + log1pf(__expf(mn - mx));
        } else {
            bool si = (dsi == 2);
            bool smv = (dsm != 0);
            float a0 = (smv || si)  ? NEGV : dl0;
            float a1 = (smv || !si) ? NEGV : dl1;
            float mx = fmaxf(a0, a1), mn = fminf(a0, a1);
            sc = mx + log1pf(__expf(mn - mx));
        }
        Lc[cstart(w) + tid] = K2f * sc + m + __log2f(ss);
    }
}

// one level with compile-time KK (entries per lane), E = 257-w in (64*(KK-1), 64*KK]
template <int KK>
__device__ __forceinline__ void level_kk(
    float* __restrict__ Lc, float* __restrict__ scr,
    const float* __restrict__ logits, const int* __restrict__ spans_ind,
    const void* __restrict__ span_mask, int isb, int t, int b,
    int w, int tid, int wave, int lane) {
    const int T = w - 1;
    const int E = NN + 1 - w;

    // prefetch raw D-score inputs for entry tid (consumed in finalize)
    float dl0 = 0.f, dl1 = 0.f; int dsi = 0, dsm = 0;
    if (tid < E) {
        size_t sidx = ((size_t)b * NN + tid) * NN + (tid + T);
        float2 dv = *(const float2*)(logits + 2 * sidx);
        dl0 = dv.x; dl1 = dv.y;
        if (t == 0) {
            dsi = spans_ind[sidx];
            dsm = isb ? (int)(((const unsigned char*)span_mask)[sidx])
                      : (((const int*)span_mask)[sidx]);
        }
    }

    const int C = (T + 15) >> 4;
    const int u0 = 1 + wave * C;
    const int u1 = min(u0 + C, w);
    const int steps = u1 - u0;

    float M[KK], S[KK];
#pragma unroll
    for (int k = 0; k < KK; ++k) { M[k] = NEGB; S[k] = 0.f; }

    if (steps > 0) {
        const int v0 = w - u0;
        int la = cstart(u0) + lane;
        int ra = cstart(v0) + u0 + lane;
        int A = 257 - u0;
        int B = 257 - v0;
        for (int it = steps >> 2; it > 0; --it) {
            const int la1 = la + A, la2 = la1 + A - 1, la3 = la2 + A - 2;
            const int ra1 = ra - B, ra2 = ra1 - B - 1, ra3 = ra2 - B - 2;
            float tv[KK][4];
#pragma unroll
            for (int k = 0; k < KK; ++k) {
                float lx0 = Lc[la  + 64 * k], lx1 = Lc[la1 + 64 * k];
                float lx2 = Lc[la2 + 64 * k], lx3 = Lc[la3 + 64 * k];
                float rx0 = Lc[ra  + 64 * k], rx1 = Lc[ra1 + 64 * k];
                float rx2 = Lc[ra2 + 64 * k], rx3 = Lc[ra3 + 64 * k];
                tv[k][0] = lx0 + rx0; tv[k][1] = lx1 + rx1;
                tv[k][2] = lx2 + rx2; tv[k][3] = lx3 + rx3;
            }
#pragma unroll
            for (int k = 0; k < KK; ++k) {
                float lm = fmaxf(fmaxf(tv[k][0], tv[k][1]),
                                 fmaxf(tv[k][2], tv[k][3]));
                float nm = fmaxf(M[k], lm);
                float e0 = fexp2(tv[k][0] - nm), e1 = fexp2(tv[k][1] - nm);
                float e2 = fexp2(tv[k][2] - nm), e3 = fexp2(tv[k][3] - nm);
                S[k] = S[k] * fexp2(M[k] - nm) + ((e0 + e1) + (e2 + e3));
                M[k] = nm;
            }
            la += 4 * A - 6; A -= 4;
            ra -= 4 * B + 6; B += 4;
        }
        for (int rem = steps & 3; rem > 0; --rem) {
#pragma unroll
            for (int k = 0; k < KK; ++k) {
                float tv0 = Lc[la + 64 * k] + Lc[ra + 64 * k];
                float nm = fmaxf(M[k], tv0);
                S[k] = S[k] * fexp2(M[k] - nm) + fexp2(tv0 - nm);
                M[k] = nm;
            }
            la += A; A -= 1;
            ra -= B; B += 1;
        }
    }

    // compressed partial per (wave, entry): m + log2(s)  [stride-1, masked]
#pragma unroll
    for (int k = 0; k < KK; ++k) {
        int g = lane + 64 * k;
        if (g < E) scr[(wave << 8) + g] = M[k] + __log2f(S[k]);
    }
    __syncthreads();

    finalize_level(Lc, scr, w, E, tid, t, dl0, dl1, dsi, dsm);
    __syncthreads();
}

// small-E path (w >= 193, E <= 64): round-6 sub-grouped logic
__device__ __forceinline__ void level_small(
    float* __restrict__ Lc, float* __restrict__ scr,
    const float* __restrict__ logits, const int* __restrict__ spans_ind,
    const void* __restrict__ span_mask, int isb, int t, int b,
    int w, int tid, int wave, int lane) {
    const int T = w - 1;
    const int E = NN + 1 - w;

    float dl0 = 0.f, dl1 = 0.f; int dsi = 0, dsm = 0;
    if (tid < E) {
        size_t sidx = ((size_t)b * NN + tid) * NN + (tid + T);
        float2 dv = *(const float2*)(logits + 2 * sidx);
        dl0 = dv.x; dl1 = dv.y;
        if (t == 0) {
            dsi = spans_ind[sidx];
            dsm = isb ? (int)(((const unsigned char*)span_mask)[sidx])
                      : (((const int*)span_mask)[sidx]);
        }
    }

    const int EH = (E <= 1) ? 1 : (1 << (32 - __clz(E - 1)));  // pow2 >= E
    const int sh2 = (EH == 1) ? 0 : (31 - __clz(EH));
    const int g = lane & (EH - 1);
    const int slot = (wave << (6 - sh2)) + (lane >> sh2);
    const int slots_sh = 10 - sh2;
    const int C = (T + (1 << slots_sh) - 1) >> slots_sh;
    const int u0 = 1 + slot * C;
    const int u1 = min(u0 + C, w);
    const int steps = u1 - u0;

    float M0 = NEGB, S0 = 0.f;
    if (steps > 0) {
        const int v0 = w - u0;
        int la = cstart(u0) + g;
        int ra = cstart(v0) + g + u0;
        int A = 257 - u0;
        int B = 257 - v0;
        for (int it = steps; it > 0; --it) {
            float tv0 = Lc[la] + Lc[ra];
            float nm = fmaxf(M0, tv0);
            S0 = S0 * fexp2(M0 - nm) + fexp2(tv0 - nm);
            M0 = nm;
            la += A; A -= 1;
            ra -= B; B += 1;
        }
    }
    // butterfly across sub-groups (same g, different u-chunks)
    for (int d = 32; d >= EH; d >>= 1) {
        float mm = __shfl_xor(M0, d);
        float ss = __shfl_xor(S0, d);
        float nm = fmaxf(M0, mm);
        S0 = S0 * fexp2(M0 - nm) + ss * fexp2(mm - nm);
        M0 = nm;
    }
    if ((lane >> sh2) == 0)
        scr[(wave << 8) + g] = M0 + __log2f(S0);
    __syncthreads();

    finalize_level(Lc, scr, w, E, tid, t, dl0, dl1, dsi, dsm);
    __syncthreads();
}

template <bool USE_LDS>
__global__ __launch_bounds__(1024) void cyk_kernel(
    const float* __restrict__ logits,     // [B,N,N,2] f32
    const int* __restrict__ spans_ind,    // [B,N,N] i32
    const void* __restrict__ maskspan,    // [B,N,N] bool (byte or i32)
    const void* __restrict__ span_mask,   // [B,N,N] bool
    float* __restrict__ ws) {
    extern __shared__ float lds[];
    const int c = blockIdx.x;
    const int b = c >> 1;
    const int t = c & 1;
    const int tid = threadIdx.x;
    const int wave = tid >> 6, lane = tid & 63;

    float* __restrict__ Lc = USE_LDS ? lds : (ws + FB_OFF + (size_t)c * LDSF);
    float* __restrict__ scr = Lc + SCR_OFF;

    __shared__ int s_len;
    __shared__ int s_isb;
    if (tid == 0) {
        s_len = 0;
        unsigned probe = *(const unsigned*)maskspan;
        s_isb = (probe > 1u) ? 1 : 0;  // byte-packed bools -> 0x01010101
    }
    __syncthreads();
    const int isb = s_isb;

    // lens[b] = sum_j maskspan[b,0,j]
    if (tid < NN) {
        size_t off = (size_t)b * NN * NN + tid;
        int v = isb ? (((const unsigned char*)maskspan)[off] ? 1 : 0)
                    : (((const int*)maskspan)[off] ? 1 : 0);
        atomicAdd(&s_len, v);
    }

    // width-1 column init (base-2 domain): col 1 starts at 0
    if (tid < NN) {
        Lc[tid] = K2f *
            score_at(logits, spans_ind, span_mask, isb, t, b, tid, tid);
    }
    __syncthreads();

    for (int w = 2; w <= 64; ++w)
        level_kk<4>(Lc, scr, logits, spans_ind, span_mask, isb, t, b,
                    w, tid, wave, lane);
    for (int w = 65; w <= 128; ++w)
        level_kk<3>(Lc, scr, logits, spans_ind, span_mask, isb, t, b,
                    w, tid, wave, lane);
    for (int w = 129; w <= 192; ++w)
        level_kk<2>(Lc, scr, logits, spans_ind, span_mask, isb, t, b,
                    w, tid, wave, lane);
    for (int w = 193; w <= NN; ++w)
        level_small(Lc, scr, logits, spans_ind, span_mask, isb, t, b,
                    w, tid, wave, lane);

    if (tid == 0) {
        int len = s_len;
        float rres = (len >= 1) ? (Lc[cstart(len)] * LN2f) : NEGV;
        ws[RES_OFF + c] = rres;
        if (t == 0) ws[LEN_OFF + b] = (float)len;
    }
}

__global__ __launch_bounds__(64) void finish_kernel(const float* __restrict__ ws,
                                                    float* __restrict__ out) {
    int b = threadIdx.x;  // 0..63
    float diff = ws[RES_OFF + 2 * b + 1] - ws[RES_OFF + 2 * b];
    float len  = ws[LEN_OFF + b];
    for (int d = 32; d > 0; d >>= 1) {
        diff += __shfl_xor(diff, d);
        len  += __shfl_xor(len, d);
    }
    if (b == 0) out[0] = diff / len;
}

extern "C" void kernel_launch(void* const* d_in, const int* in_sizes, int n_in,
                              void* d_out, int out_size, void* d_ws, size_t ws_size,
                              hipStream_t stream) {
    const float* logits    = (const float*)d_in[0];
    const int*   spans_ind = (const int*)d_in[1];
    const void*  maskspan  = d_in[2];
    const void*  span_mask = d_in[3];
    float* ws = (float*)d_ws;

    const size_t shbytes = (size_t)LDSF * sizeof(float);  // 147968 B
    hipError_t e = hipFuncSetAttribute(
        reinterpret_cast<const void*>(&cyk_kernel<true>),
        hipFuncAttributeMaxDynamicSharedMemorySize, (int)shbytes);
    if (e == hipSuccess) {
        hipLaunchKernelGGL(cyk_kernel<true>, dim3(NCHART), dim3(1024), shbytes,
                           stream, logits, spans_ind, maskspan, span_mask, ws);
    } else {
        hipLaunchKernelGGL(cyk_kernel<false>, dim3(NCHART), dim3(1024), 0,
                           stream, logits, spans_ind, maskspan, span_mask, ws);
    }
    hipLaunchKernelGGL(finish_kernel, dim3(1), dim3(64), 0, stream,
                       ws, (float*)d_out);
}